// Round 3
// baseline (149.449 us; speedup 1.0000x reference)
//
#include <hip/hip_runtime.h>
#include <hip/hip_bf16.h>

// Problem: AdditiveMul  (N_Q=2048, N_K=2048, N_HEAD=8, D_HEAD=64)
// out[i,j,h] = softmax_h( relu( dot(q[i,h,:], attn[0,h,0:64]) + dot(k[j,h,:], attn[0,h,64:128]) ) )
// Output: (2048, 2048, 8) f32 = 134 MB -> store-bandwidth bound (~21 us floor at 6.3 TB/s).
//
// R1/R2: each softmax thread writes exactly ONE float4 (dense 16 B/lane ->
// 1024 B fully-dense per wave store instruction), non-temporal to avoid L2
// allocate/evict churn on the 134 MB streaming write.
// R2 fix: __builtin_nontemporal_store needs a native vector type, not HIP float4.

#define N_Q   2048
#define N_K   2048
#define N_HEAD 8
#define D_HEAD 64

typedef float v4f __attribute__((ext_vector_type(4)));

// ---------------------------------------------------------------------------
// Kernel 1: sq[i,h] = dot(q[i,h,:], attn[h,0:64]); sk[j,h] = dot(k[j,h,:], attn[h,64:128])
// 8 lanes per (row,head); float4 loads; shuffle-reduce. ~16 MB read, a few us.
// ---------------------------------------------------------------------------
__global__ __launch_bounds__(256) void proj_kernel(
    const float* __restrict__ q, const float* __restrict__ k,
    const float* __restrict__ attn,
    float* __restrict__ sq, float* __restrict__ sk)
{
    int tid = blockIdx.x * blockDim.x + threadIdx.x;
    int lane8 = tid & 7;
    int pair  = tid >> 3;                 // [0, 2*N_Q*N_HEAD)
    const int PAIRS = N_Q * N_HEAD;
    bool is_k = pair >= PAIRS;
    int p = is_k ? (pair - PAIRS) : pair; // p = row*8 + h
    int h = p & (N_HEAD - 1);

    const float* src = is_k ? k : q;
    const float* a   = attn + h * (2 * D_HEAD) + (is_k ? D_HEAD : 0);

    const float4* s4 = (const float4*)(src + (size_t)p * D_HEAD + lane8 * 8);
    const float4* a4 = (const float4*)(a + lane8 * 8);
    float4 x0 = s4[0], x1 = s4[1];
    float4 w0 = a4[0], w1 = a4[1];
    float sum = x0.x*w0.x + x0.y*w0.y + x0.z*w0.z + x0.w*w0.w
              + x1.x*w1.x + x1.y*w1.y + x1.z*w1.z + x1.w*w1.w;

    sum += __shfl_xor(sum, 1);
    sum += __shfl_xor(sum, 2);
    sum += __shfl_xor(sum, 4);

    if (lane8 == 0) {
        (is_k ? sk : sq)[p] = sum;
    }
}

// ---------------------------------------------------------------------------
// Kernel 2: one thread per (i, j, half). Computes the full 8-head softmax
// (cheap; needed for the denominator) but stores only its 4-head half as a
// single dense non-temporal float4.
// ---------------------------------------------------------------------------
__global__ __launch_bounds__(256) void softmax_kernel(
    const float* __restrict__ sq, const float* __restrict__ sk,
    float* __restrict__ out)
{
    int t = blockIdx.x * blockDim.x + threadIdx.x;   // 0 .. 2*N_K-1
    int j    = t >> 1;
    int half = t & 1;
    int i = blockIdx.y;

    // sq[i,:] broadcast (block-uniform); sk[j,:] L1/L2-resident (64 KB table)
    float4 q0 = *(const float4*)(sq + i * N_HEAD);
    float4 q1 = *(const float4*)(sq + i * N_HEAD + 4);
    float4 k0 = *(const float4*)(sk + j * N_HEAD);
    float4 k1 = *(const float4*)(sk + j * N_HEAD + 4);

    float v[8];
    v[0] = q0.x + k0.x; v[1] = q0.y + k0.y; v[2] = q0.z + k0.z; v[3] = q0.w + k0.w;
    v[4] = q1.x + k1.x; v[5] = q1.y + k1.y; v[6] = q1.z + k1.z; v[7] = q1.w + k1.w;

    float m = 0.0f;   // relu floor: max >= 0
    #pragma unroll
    for (int h = 0; h < 8; ++h) {
        v[h] = fmaxf(v[h], 0.0f);
        m = fmaxf(m, v[h]);
    }
    float s = 0.0f;
    #pragma unroll
    for (int h = 0; h < 8; ++h) {
        v[h] = __expf(v[h] - m);
        s += v[h];
    }
    float inv = 1.0f / s;

    int b = half * 4;
    v4f o;
    o.x = v[b]*inv; o.y = v[b+1]*inv; o.z = v[b+2]*inv; o.w = v[b+3]*inv;

    float* dst = out + ((size_t)i * N_K + j) * N_HEAD + b;
    __builtin_nontemporal_store(o, (v4f*)dst);
}

extern "C" void kernel_launch(void* const* d_in, const int* in_sizes, int n_in,
                              void* d_out, int out_size, void* d_ws, size_t ws_size,
                              hipStream_t stream) {
    const float* q    = (const float*)d_in[0];
    const float* k    = (const float*)d_in[1];
    const float* attn = (const float*)d_in[2];
    float* out = (float*)d_out;

    float* sq = (float*)d_ws;            // N_Q*N_HEAD floats
    float* sk = sq + N_Q * N_HEAD;       // N_K*N_HEAD floats

    int total_threads = 2 * N_Q * N_HEAD * 8;   // 262144
    proj_kernel<<<dim3(total_threads / 256), dim3(256), 0, stream>>>(q, k, attn, sq, sk);

    // 2 float4-writers per (i,j): grid.x = 2*N_K/256 = 16, grid.y = N_Q
    softmax_kernel<<<dim3(2 * N_K / 256, N_Q), dim3(256), 0, stream>>>(sq, sk, out);
}